// Round 3
// baseline (86.048 us; speedup 1.0000x reference)
//
#include <hip/hip_runtime.h>
#include <stdint.h>

// ALCOVE RBF: out[b,e] = exp(-C * sum_d attn[d] * |E[e,d] - X[b,d]|)
// BATCH=2048, NE=2048, ND=128, f32 in/out.
//
// R3: LDS-bandwidth was the R2 limiter (2 B/term). Fix: wave-uniform X rows
// (LDS same-address broadcast = free) + 8x4 micro-tile -> 0.52 B/term, which
// puts VALU (1 v_sad_u32 per term) back as the roofline (~6.8 us floor).
//
// Fixed-point SAD (from R2): attn >= 0 so attn_d*|x-e| == |attn_d*x-attn_d*e|;
// q(v) = (uint)(v*2^24 + 2^21 + 0.5). |attn*x|*2^24 < 2^20 << bias 2^21;
// 128-term sum < 2^29 (no overflow); bias cancels in |a-b|. Quant error on
// output ~1e-4 << 1.67e-3 threshold (R2 measured absmax 2.4e-4).
//
// Layout: block = 256 thr (4 waves), tile 32(b) x 256(e), KC=32 dims/chunk.
// Wave w owns b-rows 8w..8w+7 (wave-uniform -> Xs reads broadcast).
// Lane owns e = 4*lane..+3 -> Es read is one conflict-free ds_read_b128.
// Es padded to stride 260 words/d: reads stay 16B-aligned + conflict-free,
// staging writes drop from 16-way to 4-way conflicts (~1.6x, negligible).
// Register prefetch of chunk c+1 globals overlaps compute of chunk c.

#define BATCH 2048
#define NE 2048
#define ND 128

#define TB 32
#define TE 256
#define KC 32
#define SE 260              // Es word-stride per d (256 + 4 pad)
#define NCHUNK (ND / KC)    // 4

#define QSCALE 16777216.0f            // 2^24
#define QBIAS  2097152.5f             // 2^21 + 0.5
#define KEXP   (-6.5f / 16777216.0f)  // -C / 2^24

#define SAD(acc, a, b) asm("v_sad_u32 %0, %1, %2, %0" : "+v"(acc) : "v"(a), "v"(b))

__global__ __launch_bounds__(256, 2)
void alcove_rbf_kernel(const float* __restrict__ X,
                       const float* __restrict__ E,
                       const float* __restrict__ A,
                       float* __restrict__ out) {
  __shared__ __align__(16) uint32_t Es[KC * SE];  // [d][e] padded, 32.5 KB
  __shared__ __align__(16) uint32_t Xs[KC * TB];  // [d][b]          4 KB

  const int tid = threadIdx.x;
  const int lane = tid & 63;
  const int w = tid >> 6;              // wave id 0..3 -> b-rows 8w..8w+7
  const int e0 = blockIdx.x * TE;      // 8 e-tiles
  const int b0 = blockIdx.y * TB;      // 64 b-tiles

  const int c4 = tid & 7;              // float4 column in chunk (0..7)
  const int srow = tid >> 3;           // staging row 0..31

  uint32_t acc[8][4];
#pragma unroll
  for (int j = 0; j < 8; ++j)
#pragma unroll
    for (int i = 0; i < 4; ++i) acc[j][i] = 0u;

  // ---- prefetch chunk 0 into registers ----
  float4 eP[8], xP, aP;
  {
    aP = reinterpret_cast<const float4*>(A)[c4];
#pragma unroll
    for (int it = 0; it < 8; ++it)
      eP[it] = reinterpret_cast<const float4*>(
                   E + (size_t)(e0 + it * 32 + srow) * ND)[c4];
    xP = reinterpret_cast<const float4*>(X + (size_t)(b0 + srow) * ND)[c4];
  }

#pragma unroll 1
  for (int c = 0; c < NCHUNK; ++c) {
    if (c) __syncthreads();            // LDS safe to overwrite

    // ---- stage regs -> LDS (quantize to biased fixed point) ----
    float4 as;
    as.x = aP.x * QSCALE; as.y = aP.y * QSCALE;
    as.z = aP.z * QSCALE; as.w = aP.w * QSCALE;
    const int dbase = 4 * c4;
#pragma unroll
    for (int it = 0; it < 8; ++it) {
      int row = it * 32 + srow;
      Es[(dbase + 0) * SE + row] = (uint32_t)fmaf(eP[it].x, as.x, QBIAS);
      Es[(dbase + 1) * SE + row] = (uint32_t)fmaf(eP[it].y, as.y, QBIAS);
      Es[(dbase + 2) * SE + row] = (uint32_t)fmaf(eP[it].z, as.z, QBIAS);
      Es[(dbase + 3) * SE + row] = (uint32_t)fmaf(eP[it].w, as.w, QBIAS);
    }
    Xs[(dbase + 0) * TB + srow] = (uint32_t)fmaf(xP.x, as.x, QBIAS);
    Xs[(dbase + 1) * TB + srow] = (uint32_t)fmaf(xP.y, as.y, QBIAS);
    Xs[(dbase + 2) * TB + srow] = (uint32_t)fmaf(xP.z, as.z, QBIAS);
    Xs[(dbase + 3) * TB + srow] = (uint32_t)fmaf(xP.w, as.w, QBIAS);
    __syncthreads();

    // ---- prefetch next chunk (waits sink to next staging) ----
    if (c + 1 < NCHUNK) {
      const int kn = (c + 1) * KC;
      aP = reinterpret_cast<const float4*>(A + kn)[c4];
#pragma unroll
      for (int it = 0; it < 8; ++it)
        eP[it] = reinterpret_cast<const float4*>(
                     E + (size_t)(e0 + it * 32 + srow) * ND + kn)[c4];
      xP = reinterpret_cast<const float4*>(X + (size_t)(b0 + srow) * ND + kn)[c4];
    }

    // ---- compute: 32 SADs per lane per d ----
    const uint4* Es4 = reinterpret_cast<const uint4*>(Es);
    const uint4* Xs4 = reinterpret_cast<const uint4*>(Xs);
#pragma unroll 8
    for (int d = 0; d < KC; ++d) {
      uint4 ev = Es4[d * (SE / 4) + lane];        // conflict-free, contiguous
      uint4 xa = Xs4[d * (TB / 4) + 2 * w];       // wave-uniform broadcast
      uint4 xb = Xs4[d * (TB / 4) + 2 * w + 1];
      SAD(acc[0][0], xa.x, ev.x); SAD(acc[0][1], xa.x, ev.y);
      SAD(acc[0][2], xa.x, ev.z); SAD(acc[0][3], xa.x, ev.w);
      SAD(acc[1][0], xa.y, ev.x); SAD(acc[1][1], xa.y, ev.y);
      SAD(acc[1][2], xa.y, ev.z); SAD(acc[1][3], xa.y, ev.w);
      SAD(acc[2][0], xa.z, ev.x); SAD(acc[2][1], xa.z, ev.y);
      SAD(acc[2][2], xa.z, ev.z); SAD(acc[2][3], xa.z, ev.w);
      SAD(acc[3][0], xa.w, ev.x); SAD(acc[3][1], xa.w, ev.y);
      SAD(acc[3][2], xa.w, ev.z); SAD(acc[3][3], xa.w, ev.w);
      SAD(acc[4][0], xb.x, ev.x); SAD(acc[4][1], xb.x, ev.y);
      SAD(acc[4][2], xb.x, ev.z); SAD(acc[4][3], xb.x, ev.w);
      SAD(acc[5][0], xb.y, ev.x); SAD(acc[5][1], xb.y, ev.y);
      SAD(acc[5][2], xb.y, ev.z); SAD(acc[5][3], xb.y, ev.w);
      SAD(acc[6][0], xb.z, ev.x); SAD(acc[6][1], xb.z, ev.y);
      SAD(acc[6][2], xb.z, ev.z); SAD(acc[6][3], xb.z, ev.w);
      SAD(acc[7][0], xb.w, ev.x); SAD(acc[7][1], xb.w, ev.y);
      SAD(acc[7][2], xb.w, ev.z); SAD(acc[7][3], xb.w, ev.w);
    }
  }

  // ---- epilogue: exp + coalesced float4 stores ----
  // lane's outputs: b = b0+8w+j (wave-uniform rows), e = e0+4*lane+i
#pragma unroll
  for (int j = 0; j < 8; ++j) {
    int b = b0 + 8 * w + j;
    float4 o;
    o.x = __expf(KEXP * (float)acc[j][0]);
    o.y = __expf(KEXP * (float)acc[j][1]);
    o.z = __expf(KEXP * (float)acc[j][2]);
    o.w = __expf(KEXP * (float)acc[j][3]);
    reinterpret_cast<float4*>(out + (size_t)b * NE + e0)[lane] = o;
  }
}

extern "C" void kernel_launch(void* const* d_in, const int* in_sizes, int n_in,
                              void* d_out, int out_size, void* d_ws, size_t ws_size,
                              hipStream_t stream) {
  const float* X = (const float*)d_in[0];   // inputs    (2048,128)
  const float* E = (const float*)d_in[1];   // exemplars (2048,128)
  const float* A = (const float*)d_in[2];   // attn      (128,)
  float* out = (float*)d_out;               // (2048,2048)

  dim3 grid(NE / TE, BATCH / TB);           // (8,64) = 512 blocks = 2/CU
  dim3 block(256);
  alcove_rbf_kernel<<<grid, block, 0, stream>>>(X, E, A, out);
}